// Round 6
// baseline (329.091 us; speedup 1.0000x reference)
//
#include <hip/hip_runtime.h>
#include <cstdint>

typedef __bf16 bf16;
typedef __attribute__((ext_vector_type(8))) __bf16 bf16x8;
typedef __attribute__((ext_vector_type(4))) __bf16 bf16x4;
typedef __attribute__((ext_vector_type(4))) float f32x4;

#define NROWS 100000
#define DIM   512
#define NC    400

// ---- workspace layout (bytes) ---- (proven ws >= 71041536)
#define WS_WP    0u          // packed W bf16: 16*4*448*8 = 458752 B
#define WS_SUMU  458752u
#define WS_SUMV  459152u
#define WS_DSC   459552u
#define WS_VTZT  459776u     // [112][128] bf16
#define WS_U     524288u     // [100000][128] bf16
#define WS_VT    26124288u   // V^T [100][100000] bf16
#define WS_ZT    46124288u   // Z^T [100][100000] bf16
#define WS_PART  66124288u   // 98 x 12544 f32 (atomic-accumulated)
#define WS_NEED  71041536u

__device__ __forceinline__ void gload_lds16(const void* g, void* l) {
  __builtin_amdgcn_global_load_lds(
      (const __attribute__((address_space(1))) uint32_t*)g,
      (__attribute__((address_space(3))) uint32_t*)l,
      16, 0, 0);
}

// ---- k1: pack W -> [t][g][448 col][8 e] bf16 (28672 B per tile t); zero sums ----
__global__ void k1_prep(const float* __restrict__ W, bf16* __restrict__ wp,
                        float* __restrict__ sums) {
  const int idx = blockIdx.x * 256 + threadIdx.x;
  if (idx < 200) sums[idx] = 0.f;
  if (idx >= 16 * 4 * 448 * 8) return;
  const int e = idx & 7;
  int r = idx >> 3;
  const int col = r % 448; r /= 448;
  const int g = r & 3;
  const int t = r >> 2;
  const int k = t * 32 + 4 * g + ((e < 4) ? e : (12 + e));
  wp[idx] = (bf16)((col < NC) ? W[col * DIM + k] : 0.f);
}

// ---- k2 (3-arm ablation): relu(X@Wt+b). BM=64 x BN=448, BK=32, 8 waves.
// V0: counted vmcnt (round-5 control)   V1: vmcnt(0) synchronous
// V2: V0 K-loop + LDS-transposed coalesced Vt/Zt epilogue
template <int VARIANT>
__global__ __launch_bounds__(512, 4) void k2_main(
    const float* __restrict__ X, const bf16* __restrict__ Wp,
    const float* __restrict__ bias, float* __restrict__ out,
    bf16* __restrict__ U, bf16* __restrict__ Vt, bf16* __restrict__ Zt,
    float* __restrict__ sumU, float* __restrict__ sumV, int blk0) {
  __shared__ __align__(16) float Ab[3][2048];   // 3 x 8 KB
  __shared__ __align__(16) bf16  Bb[2][14336];  // 2 x 28 KB  (total 80 KB)

  const int tid  = threadIdx.x;
  const int lane = tid & 63;
  const int wave = tid >> 6;         // 0..7
  const int wm = wave >> 2;          // 0..1 : 32-row half
  const int wn = wave & 3;           // 0..3 : 112-col quarter
  const int m  = lane & 15;
  const int g  = lane >> 4;
  const int rb = (blk0 + blockIdx.x) * 64;

  f32x4 acc[2][7];
#pragma unroll
  for (int i = 0; i < 2; ++i)
#pragma unroll
    for (int j = 0; j < 7; ++j) acc[i][j] = (f32x4){0.f, 0.f, 0.f, 0.f};

  const int arow = wave * 8 + (lane >> 3);
  int gr = rb + arow; if (gr > NROWS - 1) gr = NROWS - 1;
  const char* asrc = (const char*)X + (size_t)gr * 2048 + (size_t)(((lane & 7) ^ (lane >> 3)) * 16);
  const int bc0 = (wave < 4) ? wave * 4 : 16 + (wave - 4) * 3;
  const int nbc = (wave < 4) ? 4 : 3;
  const char* wpc = (const char*)Wp;

#define STAGE_A(T, BUF) \
  gload_lds16(asrc + (size_t)(T) * 128, (char*)&Ab[BUF][0] + wave * 1024 + lane * 16)
#define STAGE_B(T, BUF)                                                        \
  do {                                                                         \
    const char* bsrc = wpc + (size_t)(T) * 28672;                              \
    for (int q = 0; q < nbc; ++q)                                              \
      gload_lds16(bsrc + (bc0 + q) * 1024 + lane * 16,                         \
                  (char*)&Bb[BUF][0] + (bc0 + q) * 1024);                      \
  } while (0)

  STAGE_A(0, 0);
  STAGE_B(0, 0);
  STAGE_A(1, 1);

#pragma unroll
  for (int t = 0; t < 16; ++t) {
    const int ab  = t % 3;
    const int bb_ = t & 1;
    if (t < 15) STAGE_B(t + 1, bb_ ^ 1);
    if (t < 14) STAGE_A(t + 2, (t + 2) % 3);
    if constexpr (VARIANT == 1) {
      asm volatile("s_waitcnt vmcnt(0)\n\ts_barrier" ::: "memory");
    } else {
      if (t < 14) {
        if (wave < 4) asm volatile("s_waitcnt vmcnt(6)\n\ts_barrier" ::: "memory");
        else          asm volatile("s_waitcnt vmcnt(5)\n\ts_barrier" ::: "memory");
      } else if (t == 14) {
        if (wave < 4) asm volatile("s_waitcnt vmcnt(5)\n\ts_barrier" ::: "memory");
        else          asm volatile("s_waitcnt vmcnt(4)\n\ts_barrier" ::: "memory");
      } else {
        asm volatile("s_waitcnt vmcnt(0)\n\ts_barrier" ::: "memory");
      }
    }

    const int sw = (m & 7) * 16;
    const char* row0 = (const char*)&Ab[ab][0] + (wm * 32 + m) * 128;
    const char* row1 = row0 + 16 * 128;
    f32x4 a0lo = *(const f32x4*)(row0 + ((16 * g) ^ sw));
    f32x4 a0hi = *(const f32x4*)(row0 + ((64 + 16 * g) ^ sw));
    f32x4 a1lo = *(const f32x4*)(row1 + ((16 * g) ^ sw));
    f32x4 a1hi = *(const f32x4*)(row1 + ((64 + 16 * g) ^ sw));
    bf16x8 af0 = {(bf16)a0lo.x, (bf16)a0lo.y, (bf16)a0lo.z, (bf16)a0lo.w,
                  (bf16)a0hi.x, (bf16)a0hi.y, (bf16)a0hi.z, (bf16)a0hi.w};
    bf16x8 af1 = {(bf16)a1lo.x, (bf16)a1lo.y, (bf16)a1lo.z, (bf16)a1lo.w,
                  (bf16)a1hi.x, (bf16)a1hi.y, (bf16)a1hi.z, (bf16)a1hi.w};

    const bf16* Bc = &Bb[bb_][0];
#pragma unroll
    for (int nf = 0; nf < 7; ++nf) {
      const int n = wn * 112 + nf * 16 + m;
      bf16x8 bfr = *(const bf16x8*)(Bc + (g * 448 + n) * 8);
      acc[0][nf] = __builtin_amdgcn_mfma_f32_16x16x32_bf16(af0, bfr, acc[0][nf], 0, 0, 0);
      acc[1][nf] = __builtin_amdgcn_mfma_f32_16x16x32_bf16(af1, bfr, acc[1][nf], 0, 0, 0);
    }
    asm volatile("s_barrier" ::: "memory");
  }
#undef STAGE_A
#undef STAGE_B

  // ---- epilogue ----
  bf16* ldsT = (bf16*)&Bb[0][0];    // V2: [200 cols][72 rows] bf16 = 28800 B (dead B bufs)
  float csum[7];
#pragma unroll
  for (int nf = 0; nf < 7; ++nf) csum[nf] = 0.f;

#pragma unroll
  for (int mf = 0; mf < 2; ++mf) {
#pragma unroll
    for (int nf = 0; nf < 7; ++nf) {
      const int c = wn * 112 + nf * 16 + m;
      const float bv = (c < NC) ? bias[c] : 0.f;
#pragma unroll
      for (int r = 0; r < 4; ++r) {
        const int rl = wm * 32 + mf * 16 + 4 * g + r;   // local row 0..63
        const int row = rb + rl;
        float v = fmaxf(acc[mf][nf][r] + bv, 0.f);
        if (row < NROWS) {
          if (c < 128) U[(size_t)row * 128 + c] = (c < 100) ? (bf16)v : (bf16)0.f;
          if constexpr (VARIANT != 2) {
            if (c >= 100 && c < 200) Vt[(size_t)(c - 100) * NROWS + row] = (bf16)v;
            if (c >= 200 && c < 300) Zt[(size_t)(c - 200) * NROWS + row] = (bf16)v;
          }
          if (c >= 300 && c < NC)  out[(size_t)row * 200 + 100 + (c - 300)] = v;
          if (c < 200) csum[nf] += v;
        }
        if constexpr (VARIANT == 2) {
          if (c >= 100 && c < 300) ldsT[(c - 100) * 72 + rl] = (bf16)v;
        }
      }
    }
  }

  if constexpr (VARIANT == 2) {
    __syncthreads();
    // 200 cols x 8 chunks of 8 rows; coalesced 16-B column stores
    for (int s = tid; s < 1600; s += 512) {
      const int cc = s >> 3;
      const int r0 = (s & 7) * 8;
      bf16* dst = (cc < 100) ? (Vt + (size_t)cc * NROWS) : (Zt + (size_t)(cc - 100) * NROWS);
      const int grow = rb + r0;
      if (grow + 7 < NROWS) {
        *(bf16x8*)(dst + grow) = *(const bf16x8*)&ldsT[cc * 72 + r0];
      } else {
        for (int q = 0; q < 8; ++q)
          if (grow + q < NROWS) dst[grow + q] = ldsT[cc * 72 + r0 + q];
      }
    }
  }

#pragma unroll
  for (int nf = 0; nf < 7; ++nf) {
    float s = csum[nf];
    s += __shfl_xor(s, 16, 64);
    s += __shfl_xor(s, 32, 64);
    if (lane < 16) {
      const int c = wn * 112 + nf * 16 + lane;
      if (c < 100) atomicAdd(&sumU[c], s);
      else if (c < 200) atomicAdd(&sumV[c - 100], s);
    }
  }
}

// ---- k3: partial VtZ per 256-row block via MFMA; f32 atomicAdd into 98 bufs ----
__global__ __launch_bounds__(448) void k3_vtz(
    const bf16* __restrict__ Vt, const bf16* __restrict__ Zt,
    float* __restrict__ part) {
  const int lane = threadIdx.x & 63;
  const int wave = threadIdx.x >> 6;   // 0..6
  const int m = lane & 15, g = lane >> 4;
  const int rbase = blockIdx.x * 256;
  int nks = (NROWS - rbase) >> 5;
  if (nks > 8) nks = 8;

  f32x4 acc[7];
#pragma unroll
  for (int j = 0; j < 7; ++j) acc[j] = (f32x4){0.f, 0.f, 0.f, 0.f};

  const bf16* va = Vt + (size_t)(wave * 16 + m) * NROWS;
  for (int ks = 0; ks < nks; ++ks) {
    const int k0 = rbase + ks * 32 + 4 * g;
    bf16x4 A0 = *(const bf16x4*)(va + k0);
    bf16x4 A1 = *(const bf16x4*)(va + k0 + 16);
    bf16x8 af = {A0[0], A0[1], A0[2], A0[3], A1[0], A1[1], A1[2], A1[3]};
#pragma unroll
    for (int nf = 0; nf < 7; ++nf) {
      const bf16* zb = Zt + (size_t)(nf * 16 + m) * NROWS + k0;
      bf16x4 B0 = *(const bf16x4*)(zb);
      bf16x4 B1 = *(const bf16x4*)(zb + 16);
      bf16x8 bf_ = {B0[0], B0[1], B0[2], B0[3], B1[0], B1[1], B1[2], B1[3]};
      acc[nf] = __builtin_amdgcn_mfma_f32_16x16x32_bf16(af, bf_, acc[nf], 0, 0, 0);
    }
  }
  float* pb = part + (size_t)(blockIdx.x % 98) * 12544;
#pragma unroll
  for (int nf = 0; nf < 7; ++nf)
#pragma unroll
    for (int r = 0; r < 4; ++r) {
      const int ii = wave * 16 + 4 * g + r;
      const int jj = nf * 16 + m;
      atomicAdd(&pb[ii * 112 + jj], acc[nf][r]);
    }
}

// ---- k4a: Dscale ----
__global__ void k4a_norm(const float* __restrict__ sumU, const float* __restrict__ sumV,
                         float* __restrict__ dsc) {
  const int l = threadIdx.x;  // 64
  float v = 0.f;
  if (l < 50) v = sumU[l] * sumV[l] + sumU[l + 50] * sumV[l + 50];
#pragma unroll
  for (int off = 32; off > 0; off >>= 1) v += __shfl_down(v, off, 64);
  if (l == 0) dsc[0] = 1.f / (v * (1.f / (float)NROWS) + 1e-6f);
}

// ---- k4b: reduce 98 f32 partials, scale, store transposed bf16 [j][128] ----
__global__ void k4b_final(const float* __restrict__ part, const float* __restrict__ dsc,
                          bf16* __restrict__ vtzt) {
  const int idx = blockIdx.x * 256 + threadIdx.x;   // 49 blocks
  if (idx < 1792) vtzt[(idx >> 4) * 128 + 112 + (idx & 15)] = (bf16)0.f;
  if (idx >= 12544) return;
  const int i = idx / 112;
  const int j = idx % 112;
  float s = 0.f;
#pragma unroll 7
  for (int bb = 0; bb < 98; ++bb) s += part[(size_t)bb * 12544 + idx];
  vtzt[j * 128 + i] = (bf16)(s * dsc[0]);
}

// ---- k5: res = U @ VtZS -> out[:, 0:100] ----
__global__ __launch_bounds__(256) void k5_res(
    const bf16* __restrict__ U, const bf16* __restrict__ vtzt,
    float* __restrict__ out) {
  const int tid = threadIdx.x;
  const int lane = tid & 63;
  const int wave = tid >> 6;
  const int m = lane & 15, g = lane >> 4;
  const int rb = blockIdx.x * 128 + wave * 32;

  f32x4 acc[2][7];
#pragma unroll
  for (int i = 0; i < 2; ++i)
#pragma unroll
    for (int j = 0; j < 7; ++j) acc[i][j] = (f32x4){0.f, 0.f, 0.f, 0.f};

  int r0 = rb + m;      if (r0 > NROWS - 1) r0 = NROWS - 1;
  int r1 = rb + 16 + m; if (r1 > NROWS - 1) r1 = NROWS - 1;
  const bf16* u0 = U + (size_t)r0 * 128 + 4 * g;
  const bf16* u1 = U + (size_t)r1 * 128 + 4 * g;
  const bf16* vb = vtzt + 4 * g;

#pragma unroll
  for (int ks = 0; ks < 4; ++ks) {
    bf16x4 A00 = *(const bf16x4*)(u0 + ks * 32);
    bf16x4 A01 = *(const bf16x4*)(u0 + ks * 32 + 16);
    bf16x4 A10 = *(const bf16x4*)(u1 + ks * 32);
    bf16x4 A11 = *(const bf16x4*)(u1 + ks * 32 + 16);
    bf16x8 af0 = {A00[0], A00[1], A00[2], A00[3], A01[0], A01[1], A01[2], A01[3]};
    bf16x8 af1 = {A10[0], A10[1], A10[2], A10[3], A11[0], A11[1], A11[2], A11[3]};
#pragma unroll
    for (int nf = 0; nf < 7; ++nf) {
      const int n = nf * 16 + m;
      bf16x4 B0 = *(const bf16x4*)(vb + n * 128 + ks * 32);
      bf16x4 B1 = *(const bf16x4*)(vb + n * 128 + ks * 32 + 16);
      bf16x8 bfr = {B0[0], B0[1], B0[2], B0[3], B1[0], B1[1], B1[2], B1[3]};
      acc[0][nf] = __builtin_amdgcn_mfma_f32_16x16x32_bf16(af0, bfr, acc[0][nf], 0, 0, 0);
      acc[1][nf] = __builtin_amdgcn_mfma_f32_16x16x32_bf16(af1, bfr, acc[1][nf], 0, 0, 0);
    }
  }
#pragma unroll
  for (int mf = 0; mf < 2; ++mf)
#pragma unroll
    for (int nf = 0; nf < 7; ++nf)
#pragma unroll
      for (int r = 0; r < 4; ++r) {
        const int row = rb + mf * 16 + 4 * g + r;
        const int c = nf * 16 + m;
        if (row < NROWS && c < 100)
          out[(size_t)row * 200 + c] = acc[mf][nf][r];
      }
}

extern "C" void kernel_launch(void* const* d_in, const int* in_sizes, int n_in,
                              void* d_out, int out_size, void* d_ws, size_t ws_size,
                              hipStream_t stream) {
  const float* X = (const float*)d_in[0];
  const float* W = (const float*)d_in[1];
  const float* b = (const float*)d_in[2];
  float* out = (float*)d_out;
  char* ws = (char*)d_ws;
  if (ws_size < WS_NEED) return;

  bf16* wp     = (bf16*)(ws + WS_WP);
  float* sumU  = (float*)(ws + WS_SUMU);
  float* sumV  = (float*)(ws + WS_SUMV);
  float* dsc   = (float*)(ws + WS_DSC);
  bf16* vtzt   = (bf16*)(ws + WS_VTZT);
  bf16* U      = (bf16*)(ws + WS_U);
  bf16* Vtb    = (bf16*)(ws + WS_VT);
  bf16* Ztb    = (bf16*)(ws + WS_ZT);
  float* part  = (float*)(ws + WS_PART);

  k1_prep<<<896, 256, 0, stream>>>(W, wp, sumU);
  hipMemsetAsync(part, 0, 98u * 12544u * 4u, stream);
  // 3-arm within-probe A/B over disjoint row ranges (serialized on stream)
  k2_main<0><<<582, 512, 0, stream>>>(X, wp, b, out, U, Vtb, Ztb, sumU, sumV, 0);
  k2_main<1><<<198, 512, 0, stream>>>(X, wp, b, out, U, Vtb, Ztb, sumU, sumV, 582);
  k2_main<2><<<783, 512, 0, stream>>>(X, wp, b, out, U, Vtb, Ztb, sumU, sumV, 780);
  k3_vtz<<<391, 448, 0, stream>>>(Vtb, Ztb, part);
  k4a_norm<<<1, 64, 0, stream>>>(sumU, sumV, dsc);
  k4b_final<<<49, 256, 0, stream>>>(part, dsc, vtzt);
  k5_res<<<782, 256, 0, stream>>>(U, vtzt, out);
}

// Round 7
// 248.735 us; speedup vs baseline: 1.3231x; 1.3231x over previous
//
#include <hip/hip_runtime.h>
#include <cstdint>

typedef __bf16 bf16;
typedef __attribute__((ext_vector_type(8))) __bf16 bf16x8;
typedef __attribute__((ext_vector_type(4))) __bf16 bf16x4;
typedef __attribute__((ext_vector_type(4))) float f32x4;

#define NROWS 100000
#define DIM   512
#define NC    400
#define NBLK2 1563

// ---- workspace layout (bytes) ---- (ws >= 800 MB evidenced by harness poison fill)
#define WS_WP    0u          // packed W bf16: 16*4*448*8 = 458752 B
#define WS_SUMU  458752u
#define WS_SUMV  459152u
#define WS_DSC   459552u
#define WS_VTZT  459776u     // [112][128] bf16
#define WS_U     524288u     // [100000][128] bf16
#define WS_VT    26124288u   // V^T [100][100000] bf16
#define WS_ZT    46124288u   // Z^T [100][100000] bf16
#define WS_PART  66124288u   // 98 x 12544 f32 (atomic-accumulated, 4/address)
#define WS_SUMP  71041536u   // [1563][200] f32 per-block column sums = 1250400 B
#define WS_NEED  72291936u

__device__ __forceinline__ void gload_lds16(const void* g, void* l) {
  __builtin_amdgcn_global_load_lds(
      (const __attribute__((address_space(1))) uint32_t*)g,
      (__attribute__((address_space(3))) uint32_t*)l,
      16, 0, 0);
}

// ---- k1: pack W -> [t][g][448 col][8 e] bf16 (28672 B per tile t); zero sums ----
__global__ void k1_prep(const float* __restrict__ W, bf16* __restrict__ wp,
                        float* __restrict__ sums) {
  const int idx = blockIdx.x * 256 + threadIdx.x;
  if (idx < 200) sums[idx] = 0.f;
  if (idx >= 16 * 4 * 448 * 8) return;
  const int e = idx & 7;
  int r = idx >> 3;
  const int col = r % 448; r /= 448;
  const int g = r & 3;
  const int t = r >> 2;
  const int k = t * 32 + 4 * g + ((e < 4) ? e : (12 + e));
  wp[idx] = (bf16)((col < NC) ? W[col * DIM + k] : 0.f);
}

// ---- k2: relu(X@Wt+b). BM=64 x BN=448, BK=32, 8 waves.
// Round-5 K-loop (counted vmcnt, 3-buf A / 2-buf B). NO same-address atomics:
// column sums combined in LDS, written as one per-block row of sumP.
__global__ __launch_bounds__(512, 4) void k2_main(
    const float* __restrict__ X, const bf16* __restrict__ Wp,
    const float* __restrict__ bias, float* __restrict__ out,
    bf16* __restrict__ U, bf16* __restrict__ Vt, bf16* __restrict__ Zt,
    float* __restrict__ sumP) {
  __shared__ __align__(16) float Ab[3][2048];   // 3 x 8 KB
  __shared__ __align__(16) bf16  Bb[2][14336];  // 2 x 28 KB  (total 80 KB)

  const int tid  = threadIdx.x;
  const int lane = tid & 63;
  const int wave = tid >> 6;         // 0..7
  const int wm = wave >> 2;          // 0..1 : 32-row half
  const int wn = wave & 3;           // 0..3 : 112-col quarter
  const int m  = lane & 15;
  const int g  = lane >> 4;
  const int rb = blockIdx.x * 64;

  f32x4 acc[2][7];
#pragma unroll
  for (int i = 0; i < 2; ++i)
#pragma unroll
    for (int j = 0; j < 7; ++j) acc[i][j] = (f32x4){0.f, 0.f, 0.f, 0.f};

  const int arow = wave * 8 + (lane >> 3);
  int gr = rb + arow; if (gr > NROWS - 1) gr = NROWS - 1;
  const char* asrc = (const char*)X + (size_t)gr * 2048 + (size_t)(((lane & 7) ^ (lane >> 3)) * 16);
  const int bc0 = (wave < 4) ? wave * 4 : 16 + (wave - 4) * 3;
  const int nbc = (wave < 4) ? 4 : 3;
  const char* wpc = (const char*)Wp;

#define STAGE_A(T, BUF) \
  gload_lds16(asrc + (size_t)(T) * 128, (char*)&Ab[BUF][0] + wave * 1024 + lane * 16)
#define STAGE_B(T, BUF)                                                        \
  do {                                                                         \
    const char* bsrc = wpc + (size_t)(T) * 28672;                              \
    for (int q = 0; q < nbc; ++q)                                              \
      gload_lds16(bsrc + (bc0 + q) * 1024 + lane * 16,                         \
                  (char*)&Bb[BUF][0] + (bc0 + q) * 1024);                      \
  } while (0)

  STAGE_A(0, 0);
  STAGE_B(0, 0);
  STAGE_A(1, 1);

#pragma unroll
  for (int t = 0; t < 16; ++t) {
    const int ab  = t % 3;
    const int bb_ = t & 1;
    if (t < 15) STAGE_B(t + 1, bb_ ^ 1);
    if (t < 14) STAGE_A(t + 2, (t + 2) % 3);
    if (t < 14) {
      if (wave < 4) asm volatile("s_waitcnt vmcnt(6)\n\ts_barrier" ::: "memory");
      else          asm volatile("s_waitcnt vmcnt(5)\n\ts_barrier" ::: "memory");
    } else if (t == 14) {
      if (wave < 4) asm volatile("s_waitcnt vmcnt(5)\n\ts_barrier" ::: "memory");
      else          asm volatile("s_waitcnt vmcnt(4)\n\ts_barrier" ::: "memory");
    } else {
      asm volatile("s_waitcnt vmcnt(0)\n\ts_barrier" ::: "memory");
    }

    const int sw = (m & 7) * 16;
    const char* row0 = (const char*)&Ab[ab][0] + (wm * 32 + m) * 128;
    const char* row1 = row0 + 16 * 128;
    f32x4 a0lo = *(const f32x4*)(row0 + ((16 * g) ^ sw));
    f32x4 a0hi = *(const f32x4*)(row0 + ((64 + 16 * g) ^ sw));
    f32x4 a1lo = *(const f32x4*)(row1 + ((16 * g) ^ sw));
    f32x4 a1hi = *(const f32x4*)(row1 + ((64 + 16 * g) ^ sw));
    bf16x8 af0 = {(bf16)a0lo.x, (bf16)a0lo.y, (bf16)a0lo.z, (bf16)a0lo.w,
                  (bf16)a0hi.x, (bf16)a0hi.y, (bf16)a0hi.z, (bf16)a0hi.w};
    bf16x8 af1 = {(bf16)a1lo.x, (bf16)a1lo.y, (bf16)a1lo.z, (bf16)a1lo.w,
                  (bf16)a1hi.x, (bf16)a1hi.y, (bf16)a1hi.z, (bf16)a1hi.w};

    const bf16* Bc = &Bb[bb_][0];
#pragma unroll
    for (int nf = 0; nf < 7; ++nf) {
      const int n = wn * 112 + nf * 16 + m;
      bf16x8 bfr = *(const bf16x8*)(Bc + (g * 448 + n) * 8);
      acc[0][nf] = __builtin_amdgcn_mfma_f32_16x16x32_bf16(af0, bfr, acc[0][nf], 0, 0, 0);
      acc[1][nf] = __builtin_amdgcn_mfma_f32_16x16x32_bf16(af1, bfr, acc[1][nf], 0, 0, 0);
    }
    asm volatile("s_barrier" ::: "memory");
  }
#undef STAGE_A
#undef STAGE_B

  // epilogue: bias+relu, scatter U / Vt / Zt / T, column sums
  float csum[7];
#pragma unroll
  for (int nf = 0; nf < 7; ++nf) csum[nf] = 0.f;

#pragma unroll
  for (int mf = 0; mf < 2; ++mf) {
#pragma unroll
    for (int nf = 0; nf < 7; ++nf) {
      const int c = wn * 112 + nf * 16 + m;
      const float bv = (c < NC) ? bias[c] : 0.f;
#pragma unroll
      for (int r = 0; r < 4; ++r) {
        const int row = rb + wm * 32 + mf * 16 + 4 * g + r;
        float v = fmaxf(acc[mf][nf][r] + bv, 0.f);
        if (row < NROWS) {
          if (c < 128) U[(size_t)row * 128 + c] = (c < 100) ? (bf16)v : (bf16)0.f;
          if (c >= 100 && c < 200) Vt[(size_t)(c - 100) * NROWS + row] = (bf16)v;
          if (c >= 200 && c < 300) Zt[(size_t)(c - 200) * NROWS + row] = (bf16)v;
          if (c >= 300 && c < NC)  out[(size_t)row * 200 + 100 + (c - 300)] = v;
          if (c < 200) csum[nf] += v;
        }
      }
    }
  }

  // cross-wave combine in LDS (Ab dead), one non-atomic row store per block
  float* sp = (float*)&Ab[0][0];    // [8][112]
#pragma unroll
  for (int nf = 0; nf < 7; ++nf) {
    float s = csum[nf];
    s += __shfl_xor(s, 16, 64);
    s += __shfl_xor(s, 32, 64);
    if (lane < 16) sp[wave * 112 + nf * 16 + lane] = s;
  }
  __syncthreads();
  if (tid < 200) {
    const int wnc = tid / 112, cc = tid % 112;   // waves {wnc, wnc+4} own col tid
    sumP[(size_t)blockIdx.x * 200 + tid] =
        sp[wnc * 112 + cc] + sp[(wnc + 4) * 112 + cc];
  }
}

// ---- k3: partial VtZ per 256-row block via MFMA; f32 atomicAdd into 98 bufs ----
__global__ __launch_bounds__(448) void k3_vtz(
    const bf16* __restrict__ Vt, const bf16* __restrict__ Zt,
    float* __restrict__ part) {
  const int lane = threadIdx.x & 63;
  const int wave = threadIdx.x >> 6;   // 0..6
  const int m = lane & 15, g = lane >> 4;
  const int rbase = blockIdx.x * 256;
  int nks = (NROWS - rbase) >> 5;
  if (nks > 8) nks = 8;

  f32x4 acc[7];
#pragma unroll
  for (int j = 0; j < 7; ++j) acc[j] = (f32x4){0.f, 0.f, 0.f, 0.f};

  const bf16* va = Vt + (size_t)(wave * 16 + m) * NROWS;
  for (int ks = 0; ks < nks; ++ks) {
    const int k0 = rbase + ks * 32 + 4 * g;
    bf16x4 A0 = *(const bf16x4*)(va + k0);
    bf16x4 A1 = *(const bf16x4*)(va + k0 + 16);
    bf16x8 af = {A0[0], A0[1], A0[2], A0[3], A1[0], A1[1], A1[2], A1[3]};
#pragma unroll
    for (int nf = 0; nf < 7; ++nf) {
      const bf16* zb = Zt + (size_t)(nf * 16 + m) * NROWS + k0;
      bf16x4 B0 = *(const bf16x4*)(zb);
      bf16x4 B1 = *(const bf16x4*)(zb + 16);
      bf16x8 bf_ = {B0[0], B0[1], B0[2], B0[3], B1[0], B1[1], B1[2], B1[3]};
      acc[nf] = __builtin_amdgcn_mfma_f32_16x16x32_bf16(af, bf_, acc[nf], 0, 0, 0);
    }
  }
  float* pb = part + (size_t)(blockIdx.x % 98) * 12544;
#pragma unroll
  for (int nf = 0; nf < 7; ++nf)
#pragma unroll
    for (int r = 0; r < 4; ++r) {
      const int ii = wave * 16 + 4 * g + r;
      const int jj = nf * 16 + m;
      atomicAdd(&pb[ii * 112 + jj], acc[nf][r]);
    }
}

// ---- k4a0: reduce per-block sums -> sumU/sumV (no atomics) ----
__global__ void k4a0_redsum(const float* __restrict__ sumP,
                            float* __restrict__ sumU, float* __restrict__ sumV) {
  __shared__ float red[4];
  const int c = blockIdx.x;          // 0..199
  const int tid = threadIdx.x;       // 256
  float s = 0.f;
  for (int b = tid; b < NBLK2; b += 256) s += sumP[(size_t)b * 200 + c];
#pragma unroll
  for (int off = 1; off < 64; off <<= 1) s += __shfl_xor(s, off, 64);
  if ((tid & 63) == 0) red[tid >> 6] = s;
  __syncthreads();
  if (tid == 0) {
    float t = red[0] + red[1] + red[2] + red[3];
    if (c < 100) sumU[c] = t; else sumV[c - 100] = t;
  }
}

// ---- k4a: Dscale ----
__global__ void k4a_norm(const float* __restrict__ sumU, const float* __restrict__ sumV,
                         float* __restrict__ dsc) {
  const int l = threadIdx.x;  // 64
  float v = 0.f;
  if (l < 50) v = sumU[l] * sumV[l] + sumU[l + 50] * sumV[l + 50];
#pragma unroll
  for (int off = 32; off > 0; off >>= 1) v += __shfl_down(v, off, 64);
  if (l == 0) dsc[0] = 1.f / (v * (1.f / (float)NROWS) + 1e-6f);
}

// ---- k4b: reduce 98 f32 partials, scale, store transposed bf16 [j][128] ----
__global__ void k4b_final(const float* __restrict__ part, const float* __restrict__ dsc,
                          bf16* __restrict__ vtzt) {
  const int idx = blockIdx.x * 256 + threadIdx.x;   // 49 blocks
  if (idx < 1792) vtzt[(idx >> 4) * 128 + 112 + (idx & 15)] = (bf16)0.f;
  if (idx >= 12544) return;
  const int i = idx / 112;
  const int j = idx % 112;
  float s = 0.f;
#pragma unroll 7
  for (int bb = 0; bb < 98; ++bb) s += part[(size_t)bb * 12544 + idx];
  vtzt[j * 128 + i] = (bf16)(s * dsc[0]);
}

// ---- k5: res = U @ VtZS -> out[:, 0:100] ----
__global__ __launch_bounds__(256) void k5_res(
    const bf16* __restrict__ U, const bf16* __restrict__ vtzt,
    float* __restrict__ out) {
  const int tid = threadIdx.x;
  const int lane = tid & 63;
  const int wave = tid >> 6;
  const int m = lane & 15, g = lane >> 4;
  const int rb = blockIdx.x * 128 + wave * 32;

  f32x4 acc[2][7];
#pragma unroll
  for (int i = 0; i < 2; ++i)
#pragma unroll
    for (int j = 0; j < 7; ++j) acc[i][j] = (f32x4){0.f, 0.f, 0.f, 0.f};

  int r0 = rb + m;      if (r0 > NROWS - 1) r0 = NROWS - 1;
  int r1 = rb + 16 + m; if (r1 > NROWS - 1) r1 = NROWS - 1;
  const bf16* u0 = U + (size_t)r0 * 128 + 4 * g;
  const bf16* u1 = U + (size_t)r1 * 128 + 4 * g;
  const bf16* vb = vtzt + 4 * g;

#pragma unroll
  for (int ks = 0; ks < 4; ++ks) {
    bf16x4 A00 = *(const bf16x4*)(u0 + ks * 32);
    bf16x4 A01 = *(const bf16x4*)(u0 + ks * 32 + 16);
    bf16x4 A10 = *(const bf16x4*)(u1 + ks * 32);
    bf16x4 A11 = *(const bf16x4*)(u1 + ks * 32 + 16);
    bf16x8 af0 = {A00[0], A00[1], A00[2], A00[3], A01[0], A01[1], A01[2], A01[3]};
    bf16x8 af1 = {A10[0], A10[1], A10[2], A10[3], A11[0], A11[1], A11[2], A11[3]};
#pragma unroll
    for (int nf = 0; nf < 7; ++nf) {
      const int n = nf * 16 + m;
      bf16x4 B0 = *(const bf16x4*)(vb + n * 128 + ks * 32);
      bf16x4 B1 = *(const bf16x4*)(vb + n * 128 + ks * 32 + 16);
      bf16x8 bfr = {B0[0], B0[1], B0[2], B0[3], B1[0], B1[1], B1[2], B1[3]};
      acc[0][nf] = __builtin_amdgcn_mfma_f32_16x16x32_bf16(af0, bfr, acc[0][nf], 0, 0, 0);
      acc[1][nf] = __builtin_amdgcn_mfma_f32_16x16x32_bf16(af1, bfr, acc[1][nf], 0, 0, 0);
    }
  }
#pragma unroll
  for (int mf = 0; mf < 2; ++mf)
#pragma unroll
    for (int nf = 0; nf < 7; ++nf)
#pragma unroll
      for (int r = 0; r < 4; ++r) {
        const int row = rb + mf * 16 + 4 * g + r;
        const int c = nf * 16 + m;
        if (row < NROWS && c < 100)
          out[(size_t)row * 200 + c] = acc[mf][nf][r];
      }
}

extern "C" void kernel_launch(void* const* d_in, const int* in_sizes, int n_in,
                              void* d_out, int out_size, void* d_ws, size_t ws_size,
                              hipStream_t stream) {
  const float* X = (const float*)d_in[0];
  const float* W = (const float*)d_in[1];
  const float* b = (const float*)d_in[2];
  float* out = (float*)d_out;
  char* ws = (char*)d_ws;
  if (ws_size < WS_NEED) return;

  bf16* wp     = (bf16*)(ws + WS_WP);
  float* sumU  = (float*)(ws + WS_SUMU);
  float* sumV  = (float*)(ws + WS_SUMV);
  float* dsc   = (float*)(ws + WS_DSC);
  bf16* vtzt   = (bf16*)(ws + WS_VTZT);
  bf16* U      = (bf16*)(ws + WS_U);
  bf16* Vtb    = (bf16*)(ws + WS_VT);
  bf16* Ztb    = (bf16*)(ws + WS_ZT);
  float* part  = (float*)(ws + WS_PART);
  float* sumP  = (float*)(ws + WS_SUMP);

  k1_prep<<<896, 256, 0, stream>>>(W, wp, sumU);
  hipMemsetAsync(part, 0, 98u * 12544u * 4u, stream);
  k2_main<<<NBLK2, 512, 0, stream>>>(X, wp, b, out, U, Vtb, Ztb, sumP);
  k3_vtz<<<391, 448, 0, stream>>>(Vtb, Ztb, part);
  k4a0_redsum<<<200, 256, 0, stream>>>(sumP, sumU, sumV);
  k4a_norm<<<1, 64, 0, stream>>>(sumU, sumV, dsc);
  k4b_final<<<49, 256, 0, stream>>>(part, dsc, vtzt);
  k5_res<<<782, 256, 0, stream>>>(U, vtzt, out);
}

// Round 9
// 220.022 us; speedup vs baseline: 1.4957x; 1.1305x over previous
//
#include <hip/hip_runtime.h>
#include <cstdint>

typedef __bf16 bf16;
typedef __attribute__((ext_vector_type(8))) __bf16 bf16x8;
typedef __attribute__((ext_vector_type(4))) __bf16 bf16x4;
typedef __attribute__((ext_vector_type(4))) float f32x4;

#define NROWS 100000
#define DIM   512
#define NC    400
#define NBLK2 1563

// ---- workspace layout (bytes) ----
#define WS_WP    0u          // packed W bf16: 16*4*448*8 = 458752 B
#define WS_SUMU  458752u
#define WS_SUMV  459152u
#define WS_DSC   459552u
#define WS_VTZT  459776u     // [112][128] bf16
#define WS_U     524288u     // [100000][128] bf16
#define WS_PART  66124288u   // 98 x 12544 f32 (atomic-accumulated)
#define WS_SUMP  71041536u   // [1563][200] f32 per-block column sums
#define WS_NEED  72291936u

__device__ __forceinline__ void gload_lds16(const void* g, void* l) {
  __builtin_amdgcn_global_load_lds(
      (const __attribute__((address_space(1))) uint32_t*)g,
      (__attribute__((address_space(3))) uint32_t*)l,
      16, 0, 0);
}

// ---- k1: pack W -> [t][g][448 col][8 e] bf16 (28672 B per tile t); zero sums ----
__global__ void k1_prep(const float* __restrict__ W, bf16* __restrict__ wp,
                        float* __restrict__ sums) {
  const int idx = blockIdx.x * 256 + threadIdx.x;
  if (idx < 200) sums[idx] = 0.f;
  if (idx >= 16 * 4 * 448 * 8) return;
  const int e = idx & 7;
  int r = idx >> 3;
  const int col = r % 448; r /= 448;
  const int g = r & 3;
  const int t = r >> 2;
  const int k = t * 32 + 4 * g + ((e < 4) ? e : (12 + e));
  wp[idx] = (bf16)((col < NC) ? W[col * DIM + k] : 0.f);
}

// ---- k2: relu(X@Wt+b) + fused per-block VtZ partial.
// K-loop: round-7 structure VERBATIM (3-buf A / 2-buf B, explicit counted
// vmcnt asm waits + two barriers per step) — post-timing-validated in rounds
// 5 and 7. Epilogue: fused E1 (U/T stores, V/Z->LDS transpose, col sums) +
// E2 (112x112 K=64 VtZ partial MFMA + atomics), from round 8.
__global__ __launch_bounds__(512, 4) void k2_main(
    const float* __restrict__ X, const bf16* __restrict__ Wp,
    const float* __restrict__ bias, float* __restrict__ out,
    bf16* __restrict__ U, float* __restrict__ part, float* __restrict__ sumP) {
  __shared__ __align__(16) float Ab[3][2048];   // 3 x 8 KB  (epilogue: sp)
  __shared__ __align__(16) bf16  Bb[2][14336];  // 2 x 28 KB (epilogue: ldsVZ [224][72])

  const int tid  = threadIdx.x;
  const int lane = tid & 63;
  const int wave = tid >> 6;         // 0..7
  const int wm = wave >> 2;          // 0..1 : 32-row half
  const int wn = wave & 3;           // 0..3 : 112-col quarter
  const int m  = lane & 15;
  const int g  = lane >> 4;
  const int rb = blockIdx.x * 64;

  f32x4 acc[2][7];
#pragma unroll
  for (int i = 0; i < 2; ++i)
#pragma unroll
    for (int j = 0; j < 7; ++j) acc[i][j] = (f32x4){0.f, 0.f, 0.f, 0.f};

  const int arow = wave * 8 + (lane >> 3);
  int gr = rb + arow; if (gr > NROWS - 1) gr = NROWS - 1;
  const char* asrc = (const char*)X + (size_t)gr * 2048 + (size_t)(((lane & 7) ^ (lane >> 3)) * 16);
  const int bc0 = (wave < 4) ? wave * 4 : 16 + (wave - 4) * 3;
  const int nbc = (wave < 4) ? 4 : 3;
  const char* wpc = (const char*)Wp;

#define STAGE_A(T, BUF) \
  gload_lds16(asrc + (size_t)(T) * 128, (char*)&Ab[BUF][0] + wave * 1024 + lane * 16)
#define STAGE_B(T, BUF)                                                        \
  do {                                                                         \
    const char* bsrc = wpc + (size_t)(T) * 28672;                              \
    for (int q = 0; q < nbc; ++q)                                              \
      gload_lds16(bsrc + (bc0 + q) * 1024 + lane * 16,                         \
                  (char*)&Bb[BUF][0] + (bc0 + q) * 1024);                      \
  } while (0)

  // prologue: A0, B0, A1 (per-wave issue order matters for vmcnt counting)
  STAGE_A(0, 0);
  STAGE_B(0, 0);
  STAGE_A(1, 1);

#pragma unroll
  for (int t = 0; t < 16; ++t) {
    const int ab  = t % 3;
    const int bb_ = t & 1;
    if (t < 15) STAGE_B(t + 1, bb_ ^ 1);
    if (t < 14) STAGE_A(t + 2, (t + 2) % 3);
    if (t < 14) {
      if (wave < 4) asm volatile("s_waitcnt vmcnt(6)\n\ts_barrier" ::: "memory");
      else          asm volatile("s_waitcnt vmcnt(5)\n\ts_barrier" ::: "memory");
    } else if (t == 14) {
      if (wave < 4) asm volatile("s_waitcnt vmcnt(5)\n\ts_barrier" ::: "memory");
      else          asm volatile("s_waitcnt vmcnt(4)\n\ts_barrier" ::: "memory");
    } else {
      asm volatile("s_waitcnt vmcnt(0)\n\ts_barrier" ::: "memory");
    }

    // A fragments (swizzled read, f32 -> bf16)
    const int sw = (m & 7) * 16;
    const char* row0 = (const char*)&Ab[ab][0] + (wm * 32 + m) * 128;
    const char* row1 = row0 + 16 * 128;
    f32x4 a0lo = *(const f32x4*)(row0 + ((16 * g) ^ sw));
    f32x4 a0hi = *(const f32x4*)(row0 + ((64 + 16 * g) ^ sw));
    f32x4 a1lo = *(const f32x4*)(row1 + ((16 * g) ^ sw));
    f32x4 a1hi = *(const f32x4*)(row1 + ((64 + 16 * g) ^ sw));
    bf16x8 af0 = {(bf16)a0lo.x, (bf16)a0lo.y, (bf16)a0lo.z, (bf16)a0lo.w,
                  (bf16)a0hi.x, (bf16)a0hi.y, (bf16)a0hi.z, (bf16)a0hi.w};
    bf16x8 af1 = {(bf16)a1lo.x, (bf16)a1lo.y, (bf16)a1lo.z, (bf16)a1lo.w,
                  (bf16)a1hi.x, (bf16)a1hi.y, (bf16)a1hi.z, (bf16)a1hi.w};

    const bf16* Bc = &Bb[bb_][0];
#pragma unroll
    for (int nf = 0; nf < 7; ++nf) {
      const int n = wn * 112 + nf * 16 + m;
      bf16x8 bfr = *(const bf16x8*)(Bc + (g * 448 + n) * 8);
      acc[0][nf] = __builtin_amdgcn_mfma_f32_16x16x32_bf16(af0, bfr, acc[0][nf], 0, 0, 0);
      acc[1][nf] = __builtin_amdgcn_mfma_f32_16x16x32_bf16(af1, bfr, acc[1][nf], 0, 0, 0);
    }
    // protect buffers being restaged next iteration
    asm volatile("s_barrier" ::: "memory");
  }
#undef STAGE_A
#undef STAGE_B

  // ---- epilogue E1: bias+relu, U/T stores, V/Z -> LDS transposed, col sums ----
  // Safe to overwrite Bb: final loop iteration drained vmcnt(0) and ended with
  // a barrier after all waves' ds_reads completed.
  bf16* ldsVZ = (bf16*)&Bb[0][0];   // [224][72] bf16 = 32256 B (V rows 0..111, Z rows 112..223)
  float* sp   = (float*)&Ab[0][0];  // [8][112] f32
  float csum[7];
#pragma unroll
  for (int nf = 0; nf < 7; ++nf) csum[nf] = 0.f;

#pragma unroll
  for (int mf = 0; mf < 2; ++mf) {
#pragma unroll
    for (int nf = 0; nf < 7; ++nf) {
      const int c = wn * 112 + nf * 16 + m;
      const float bv = (c < NC) ? bias[c] : 0.f;
#pragma unroll
      for (int r = 0; r < 4; ++r) {
        const int rl = wm * 32 + mf * 16 + 4 * g + r;
        const int row = rb + rl;
        float v = fmaxf(acc[mf][nf][r] + bv, 0.f);
        const float v2 = (row < NROWS) ? v : 0.f;
        if (row < NROWS) {
          if (c < 128) U[(size_t)row * 128 + c] = (c < 100) ? (bf16)v : (bf16)0.f;
          if (c >= 300 && c < NC) out[(size_t)row * 200 + 100 + (c - 300)] = v;
        }
        if (c >= 100 && c < 300)
          ldsVZ[(size_t)((c < 200) ? (c - 100) : (112 + (c - 200))) * 72 + rl] = (bf16)v2;
        if (c < 200) csum[nf] += v2;
      }
    }
  }
  // zero V/Z pad rows (V rows 100..111, Z rows 212..223)
  for (int i = tid; i < 1728; i += 512) {
    const int half = i / 864, off = i % 864;
    ldsVZ[(half ? (112 * 72 + 7200) : 7200) + off] = (bf16)0.f;
  }
#pragma unroll
  for (int nf = 0; nf < 7; ++nf) {
    float s = csum[nf];
    s += __shfl_xor(s, 16, 64);
    s += __shfl_xor(s, 32, 64);
    if (lane < 16) sp[wave * 112 + nf * 16 + lane] = s;
  }
  __syncthreads();

  // ---- epilogue E2: per-block VtZ partial (112x112, K=64) + atomics ----
  if (wave < 7) {
    f32x4 acc2[7];
#pragma unroll
    for (int j = 0; j < 7; ++j) acc2[j] = (f32x4){0.f, 0.f, 0.f, 0.f};
    const bf16* vA = ldsVZ + (size_t)(wave * 16 + m) * 72;
#pragma unroll
    for (int kc = 0; kc < 2; ++kc) {
      bf16x4 a0 = *(const bf16x4*)(vA + kc * 32 + 4 * g);
      bf16x4 a1 = *(const bf16x4*)(vA + kc * 32 + 16 + 4 * g);
      bf16x8 af = {a0[0], a0[1], a0[2], a0[3], a1[0], a1[1], a1[2], a1[3]};
#pragma unroll
      for (int fj = 0; fj < 7; ++fj) {
        const bf16* vB = ldsVZ + (size_t)(112 + fj * 16 + m) * 72 + kc * 32;
        bf16x4 b0 = *(const bf16x4*)(vB + 4 * g);
        bf16x4 b1 = *(const bf16x4*)(vB + 16 + 4 * g);
        bf16x8 bf_ = {b0[0], b0[1], b0[2], b0[3], b1[0], b1[1], b1[2], b1[3]};
        acc2[fj] = __builtin_amdgcn_mfma_f32_16x16x32_bf16(af, bf_, acc2[fj], 0, 0, 0);
      }
    }
    float* pb = part + (size_t)(blockIdx.x % 98) * 12544;
#pragma unroll
    for (int fj = 0; fj < 7; ++fj)
#pragma unroll
      for (int r = 0; r < 4; ++r)
        atomicAdd(&pb[(wave * 16 + 4 * g + r) * 112 + fj * 16 + m], acc2[fj][r]);
  }
  if (tid < 200) {
    const int wnc = tid / 112, cc = tid % 112;
    sumP[(size_t)blockIdx.x * 200 + tid] =
        sp[wnc * 112 + cc] + sp[(wnc + 4) * 112 + cc];
  }
}

// ---- k4a0: reduce per-block sums -> sumU/sumV (no atomics) ----
__global__ void k4a0_redsum(const float* __restrict__ sumP,
                            float* __restrict__ sumU, float* __restrict__ sumV) {
  __shared__ float red[4];
  const int c = blockIdx.x;          // 0..199
  const int tid = threadIdx.x;       // 256
  float s = 0.f;
  for (int b = tid; b < NBLK2; b += 256) s += sumP[(size_t)b * 200 + c];
#pragma unroll
  for (int off = 1; off < 64; off <<= 1) s += __shfl_xor(s, off, 64);
  if ((tid & 63) == 0) red[tid >> 6] = s;
  __syncthreads();
  if (tid == 0) {
    float t = red[0] + red[1] + red[2] + red[3];
    if (c < 100) sumU[c] = t; else sumV[c - 100] = t;
  }
}

// ---- k4a: Dscale ----
__global__ void k4a_norm(const float* __restrict__ sumU, const float* __restrict__ sumV,
                         float* __restrict__ dsc) {
  const int l = threadIdx.x;  // 64
  float v = 0.f;
  if (l < 50) v = sumU[l] * sumV[l] + sumU[l + 50] * sumV[l + 50];
#pragma unroll
  for (int off = 32; off > 0; off >>= 1) v += __shfl_down(v, off, 64);
  if (l == 0) dsc[0] = 1.f / (v * (1.f / (float)NROWS) + 1e-6f);
}

// ---- k4b: reduce 98 f32 partials, scale, store transposed bf16 [j][128] ----
__global__ void k4b_final(const float* __restrict__ part, const float* __restrict__ dsc,
                          bf16* __restrict__ vtzt) {
  const int idx = blockIdx.x * 256 + threadIdx.x;   // 49 blocks
  if (idx < 1792) vtzt[(idx >> 4) * 128 + 112 + (idx & 15)] = (bf16)0.f;
  if (idx >= 12544) return;
  const int i = idx / 112;
  const int j = idx % 112;
  float s = 0.f;
#pragma unroll 7
  for (int bb = 0; bb < 98; ++bb) s += part[(size_t)bb * 12544 + idx];
  vtzt[j * 128 + i] = (bf16)(s * dsc[0]);
}

// ---- k5: res = U @ VtZS -> out[:, 0:100] ----
__global__ __launch_bounds__(256) void k5_res(
    const bf16* __restrict__ U, const bf16* __restrict__ vtzt,
    float* __restrict__ out) {
  const int tid = threadIdx.x;
  const int lane = tid & 63;
  const int wave = tid >> 6;
  const int m = lane & 15, g = lane >> 4;
  const int rb = blockIdx.x * 128 + wave * 32;

  f32x4 acc[2][7];
#pragma unroll
  for (int i = 0; i < 2; ++i)
#pragma unroll
    for (int j = 0; j < 7; ++j) acc[i][j] = (f32x4){0.f, 0.f, 0.f, 0.f};

  int r0 = rb + m;      if (r0 > NROWS - 1) r0 = NROWS - 1;
  int r1 = rb + 16 + m; if (r1 > NROWS - 1) r1 = NROWS - 1;
  const bf16* u0 = U + (size_t)r0 * 128 + 4 * g;
  const bf16* u1 = U + (size_t)r1 * 128 + 4 * g;
  const bf16* vb = vtzt + 4 * g;

#pragma unroll
  for (int ks = 0; ks < 4; ++ks) {
    bf16x4 A00 = *(const bf16x4*)(u0 + ks * 32);
    bf16x4 A01 = *(const bf16x4*)(u0 + ks * 32 + 16);
    bf16x4 A10 = *(const bf16x4*)(u1 + ks * 32);
    bf16x4 A11 = *(const bf16x4*)(u1 + ks * 32 + 16);
    bf16x8 af0 = {A00[0], A00[1], A00[2], A00[3], A01[0], A01[1], A01[2], A01[3]};
    bf16x8 af1 = {A10[0], A10[1], A10[2], A10[3], A11[0], A11[1], A11[2], A11[3]};
#pragma unroll
    for (int nf = 0; nf < 7; ++nf) {
      const int n = nf * 16 + m;
      bf16x4 B0 = *(const bf16x4*)(vb + n * 128 + ks * 32);
      bf16x4 B1 = *(const bf16x4*)(vb + n * 128 + ks * 32 + 16);
      bf16x8 bfr = {B0[0], B0[1], B0[2], B0[3], B1[0], B1[1], B1[2], B1[3]};
      acc[0][nf] = __builtin_amdgcn_mfma_f32_16x16x32_bf16(af0, bfr, acc[0][nf], 0, 0, 0);
      acc[1][nf] = __builtin_amdgcn_mfma_f32_16x16x32_bf16(af1, bfr, acc[1][nf], 0, 0, 0);
    }
  }
#pragma unroll
  for (int mf = 0; mf < 2; ++mf)
#pragma unroll
    for (int nf = 0; nf < 7; ++nf)
#pragma unroll
      for (int r = 0; r < 4; ++r) {
        const int row = rb + mf * 16 + 4 * g + r;
        const int c = nf * 16 + m;
        if (row < NROWS && c < 100)
          out[(size_t)row * 200 + c] = acc[mf][nf][r];
      }
}

extern "C" void kernel_launch(void* const* d_in, const int* in_sizes, int n_in,
                              void* d_out, int out_size, void* d_ws, size_t ws_size,
                              hipStream_t stream) {
  const float* X = (const float*)d_in[0];
  const float* W = (const float*)d_in[1];
  const float* b = (const float*)d_in[2];
  float* out = (float*)d_out;
  char* ws = (char*)d_ws;
  if (ws_size < WS_NEED) return;

  bf16* wp     = (bf16*)(ws + WS_WP);
  float* sumU  = (float*)(ws + WS_SUMU);
  float* sumV  = (float*)(ws + WS_SUMV);
  float* dsc   = (float*)(ws + WS_DSC);
  bf16* vtzt   = (bf16*)(ws + WS_VTZT);
  bf16* U      = (bf16*)(ws + WS_U);
  float* part  = (float*)(ws + WS_PART);
  float* sumP  = (float*)(ws + WS_SUMP);

  k1_prep<<<896, 256, 0, stream>>>(W, wp, sumU);
  hipMemsetAsync(part, 0, 98u * 12544u * 4u, stream);
  k2_main<<<NBLK2, 512, 0, stream>>>(X, wp, b, out, U, part, sumP);
  k4a0_redsum<<<200, 256, 0, stream>>>(sumP, sumU, sumV);
  k4a_norm<<<1, 64, 0, stream>>>(sumU, sumV, dsc);
  k4b_final<<<49, 256, 0, stream>>>(part, dsc, vtzt);
  k5_res<<<782, 256, 0, stream>>>(U, vtzt, out);
}

// Round 10
// 208.789 us; speedup vs baseline: 1.5762x; 1.0538x over previous
//
#include <hip/hip_runtime.h>
#include <cstdint>

typedef __bf16 bf16;
typedef __attribute__((ext_vector_type(8))) __bf16 bf16x8;
typedef __attribute__((ext_vector_type(4))) __bf16 bf16x4;
typedef __attribute__((ext_vector_type(4))) float f32x4;

#define NROWS 100000
#define DIM   512
#define NC    400
#define NBLK2 782

// ---- workspace layout (bytes) ----
#define WS_WP    0u          // packed W bf16: 16*4*448*8 = 458752 B
#define WS_SUMU  458752u
#define WS_SUMV  459152u
#define WS_DSC   459552u
#define WS_VTZT  459776u     // [112][128] bf16
#define WS_U     524288u     // [100000][128] bf16
#define WS_PART  66124288u   // 98 x 12544 f32 (atomic-accumulated)
#define WS_SUMP  71041536u   // [782][200] f32 per-block column sums = 625600 B
#define WS_NEED  71667136u

__device__ __forceinline__ void gload_lds16(const void* g, void* l) {
  __builtin_amdgcn_global_load_lds(
      (const __attribute__((address_space(1))) uint32_t*)g,
      (__attribute__((address_space(3))) uint32_t*)l,
      16, 0, 0);
}

// ---- k1: pack W -> [t][g][448 col][8 e] bf16 (28672 B per tile t); zero sums ----
__global__ void k1_prep(const float* __restrict__ W, bf16* __restrict__ wp,
                        float* __restrict__ sums) {
  const int idx = blockIdx.x * 256 + threadIdx.x;
  if (idx < 200) sums[idx] = 0.f;
  if (idx >= 16 * 4 * 448 * 8) return;
  const int e = idx & 7;
  int r = idx >> 3;
  const int col = r % 448; r /= 448;
  const int g = r & 3;
  const int t = r >> 2;
  const int k = t * 32 + 4 * g + ((e < 4) ? e : (12 + e));
  wp[idx] = (bf16)((col < NC) ? W[col * DIM + k] : 0.f);
}

// ---- k2: relu(X@Wt+b) + fused per-block VtZ partial.
// BM=128 x BN=448, BK=32, 8 waves; wave = 64 rows x 112 cols (acc[4][7],
// 28 MFMA/step). Staging machinery = round-7 validated structure: 3-buf A
// (f32, XOR swizzle, gload_lds) / 2-buf B (gload_lds), counted-vmcnt
// wait-then-barrier + trailing barrier. 1 block/CU (104 KB LDS).
__global__ __launch_bounds__(512, 2) void k2_main(
    const float* __restrict__ X, const bf16* __restrict__ Wp,
    const float* __restrict__ bias, float* __restrict__ out,
    bf16* __restrict__ U, float* __restrict__ part, float* __restrict__ sumP) {
  __shared__ __align__(16) char pool[106496];  // A: 3x16KB @0 ; B: 2x28KB @49152
  char* Abase0 = pool;                         //  epilogue: ldsVZ[224][136] @0, sp @61440
  char* Bbase0 = pool + 49152;

  const int tid  = threadIdx.x;
  const int lane = tid & 63;
  const int wave = tid >> 6;         // 0..7
  const int wm = wave >> 2;          // 0..1 : 64-row half
  const int wn = wave & 3;           // 0..3 : 112-col quarter
  const int m  = lane & 15;
  const int g  = lane >> 4;
  const int rb = blockIdx.x * 128;

  f32x4 acc[4][7];
#pragma unroll
  for (int i = 0; i < 4; ++i)
#pragma unroll
    for (int j = 0; j < 7; ++j) acc[i][j] = (f32x4){0.f, 0.f, 0.f, 0.f};

  // A staging: wave w stages rows [16w,16w+16) in 2 chunks of 8 rows;
  // lane -> row +(l>>3), 16B piece (l&7); global source byte XOR-swizzled.
  int gr0 = rb + wave * 16 + (lane >> 3);     if (gr0 > NROWS - 1) gr0 = NROWS - 1;
  int gr1 = rb + wave * 16 + 8 + (lane >> 3); if (gr1 > NROWS - 1) gr1 = NROWS - 1;
  const size_t swb = (size_t)(((lane & 7) ^ (lane >> 3)) * 16);
  const char* asrc0 = (const char*)X + (size_t)gr0 * 2048 + swb;
  const char* asrc1 = (const char*)X + (size_t)gr1 * 2048 + swb;
  // B staging: 28 chunks of 1024 B; waves 0-3 take 4, waves 4-7 take 3
  const int bc0 = (wave < 4) ? wave * 4 : 16 + (wave - 4) * 3;
  const int nbc = (wave < 4) ? 4 : 3;
  const char* wpc = (const char*)Wp;

#define STAGE_A(T, BUF)                                                        \
  do {                                                                         \
    char* ad = Abase0 + (BUF) * 16384 + wave * 2048 + lane * 16;               \
    gload_lds16(asrc0 + (size_t)(T) * 128, ad);                                \
    gload_lds16(asrc1 + (size_t)(T) * 128, ad + 1024);                         \
  } while (0)
#define STAGE_B(T, BUF)                                                        \
  do {                                                                         \
    const char* bsrc = wpc + (size_t)(T) * 28672;                              \
    for (int q = 0; q < nbc; ++q)                                              \
      gload_lds16(bsrc + (bc0 + q) * 1024 + lane * 16,                         \
                  Bbase0 + (BUF) * 28672 + (bc0 + q) * 1024);                  \
  } while (0)

  // prologue: A0, B0, A1 (per-wave issue order matters for vmcnt counting)
  STAGE_A(0, 0);
  STAGE_B(0, 0);
  STAGE_A(1, 1);

#pragma unroll
  for (int t = 0; t < 16; ++t) {
    const int ab  = t % 3;
    const int bb_ = t & 1;
    if (t < 15) STAGE_B(t + 1, bb_ ^ 1);
    if (t < 14) STAGE_A(t + 2, (t + 2) % 3);
    // steady state: queue [B(t) nbc | A(t+1) 2 | B(t+1) nbc | A(t+2) 2]
    // wait for B(t)+A(t) landed: leave nbc+4 in flight.
    if (t < 14) {
      if (wave < 4) asm volatile("s_waitcnt vmcnt(8)\n\ts_barrier" ::: "memory");
      else          asm volatile("s_waitcnt vmcnt(7)\n\ts_barrier" ::: "memory");
    } else if (t == 14) {  // queue [B14 nbc | A15 2 | B15 nbc] -> leave nbc+2
      if (wave < 4) asm volatile("s_waitcnt vmcnt(6)\n\ts_barrier" ::: "memory");
      else          asm volatile("s_waitcnt vmcnt(5)\n\ts_barrier" ::: "memory");
    } else {
      asm volatile("s_waitcnt vmcnt(0)\n\ts_barrier" ::: "memory");
    }

    // A fragments (swizzled read, f32 -> bf16), 4 m-frags
    const int sw = (m & 7) * 16;
    const char* abuf = Abase0 + ab * 16384;
    bf16x8 af[4];
#pragma unroll
    for (int mf = 0; mf < 4; ++mf) {
      const char* rowp = abuf + (wm * 64 + mf * 16 + m) * 128;
      f32x4 alo = *(const f32x4*)(rowp + ((16 * g) ^ sw));
      f32x4 ahi = *(const f32x4*)(rowp + ((64 + 16 * g) ^ sw));
      af[mf] = (bf16x8){(bf16)alo.x, (bf16)alo.y, (bf16)alo.z, (bf16)alo.w,
                        (bf16)ahi.x, (bf16)ahi.y, (bf16)ahi.z, (bf16)ahi.w};
    }

    const bf16* Bc = (const bf16*)(Bbase0 + bb_ * 28672);
#pragma unroll
    for (int nf = 0; nf < 7; ++nf) {
      const int n = wn * 112 + nf * 16 + m;
      bf16x8 bfr = *(const bf16x8*)(Bc + (g * 448 + n) * 8);
#pragma unroll
      for (int mf = 0; mf < 4; ++mf)
        acc[mf][nf] = __builtin_amdgcn_mfma_f32_16x16x32_bf16(af[mf], bfr, acc[mf][nf], 0, 0, 0);
    }
    // protect buffers being restaged next iteration
    asm volatile("s_barrier" ::: "memory");
  }
#undef STAGE_A
#undef STAGE_B

  // ---- epilogue E1: bias+relu, U/T stores, V/Z -> LDS transposed, col sums ----
  bf16* ldsVZ = (bf16*)pool;              // [224][136] bf16 = 60928 B
  float* sp   = (float*)(pool + 61440);   // [8][112] f32
  float csum[7];
#pragma unroll
  for (int nf = 0; nf < 7; ++nf) csum[nf] = 0.f;

#pragma unroll
  for (int mf = 0; mf < 4; ++mf) {
#pragma unroll
    for (int nf = 0; nf < 7; ++nf) {
      const int c = wn * 112 + nf * 16 + m;
      const float bv = (c < NC) ? bias[c] : 0.f;
#pragma unroll
      for (int r = 0; r < 4; ++r) {
        const int rl = wm * 64 + mf * 16 + 4 * g + r;   // 0..127
        const int row = rb + rl;
        float v = fmaxf(acc[mf][nf][r] + bv, 0.f);
        const float v2 = (row < NROWS) ? v : 0.f;
        if (row < NROWS) {
          if (c < 128) U[(size_t)row * 128 + c] = (c < 100) ? (bf16)v : (bf16)0.f;
          if (c >= 300 && c < NC) out[(size_t)row * 200 + 100 + (c - 300)] = v;
        }
        if (c >= 100 && c < 300)
          ldsVZ[(size_t)((c < 200) ? (c - 100) : (112 + (c - 200))) * 136 + rl] = (bf16)v2;
        if (c < 200) csum[nf] += v2;
      }
    }
  }
  // zero V/Z pad rows (V rows 100..111, Z rows 212..223), all 136 cols
  for (int i = tid; i < 3264; i += 512) {
    const int q = i / 136, off = i % 136;
    const int lrow = (q < 12) ? (100 + q) : (200 + q);
    ldsVZ[lrow * 136 + off] = (bf16)0.f;
  }
#pragma unroll
  for (int nf = 0; nf < 7; ++nf) {
    float s = csum[nf];
    s += __shfl_xor(s, 16, 64);
    s += __shfl_xor(s, 32, 64);
    if (lane < 16) sp[wave * 112 + nf * 16 + lane] = s;
  }
  __syncthreads();

  // ---- epilogue E2: per-block VtZ partial (112x112, K=128) + atomics ----
  if (wave < 7) {
    f32x4 acc2[7];
#pragma unroll
    for (int j = 0; j < 7; ++j) acc2[j] = (f32x4){0.f, 0.f, 0.f, 0.f};
    const bf16* vA = ldsVZ + (size_t)(wave * 16 + m) * 136;
#pragma unroll
    for (int kc = 0; kc < 4; ++kc) {
      bf16x4 a0 = *(const bf16x4*)(vA + kc * 32 + 4 * g);
      bf16x4 a1 = *(const bf16x4*)(vA + kc * 32 + 16 + 4 * g);
      bf16x8 af_ = {a0[0], a0[1], a0[2], a0[3], a1[0], a1[1], a1[2], a1[3]};
#pragma unroll
      for (int fj = 0; fj < 7; ++fj) {
        const bf16* vB = ldsVZ + (size_t)(112 + fj * 16 + m) * 136 + kc * 32;
        bf16x4 b0 = *(const bf16x4*)(vB + 4 * g);
        bf16x4 b1 = *(const bf16x4*)(vB + 16 + 4 * g);
        bf16x8 bf_ = {b0[0], b0[1], b0[2], b0[3], b1[0], b1[1], b1[2], b1[3]};
        acc2[fj] = __builtin_amdgcn_mfma_f32_16x16x32_bf16(af_, bf_, acc2[fj], 0, 0, 0);
      }
    }
    float* pb = part + (size_t)(blockIdx.x % 98) * 12544;
#pragma unroll
    for (int fj = 0; fj < 7; ++fj)
#pragma unroll
      for (int r = 0; r < 4; ++r)
        atomicAdd(&pb[(wave * 16 + 4 * g + r) * 112 + fj * 16 + m], acc2[fj][r]);
  }
  if (tid < 200) {
    const int wnc = tid / 112, cc = tid % 112;
    sumP[(size_t)blockIdx.x * 200 + tid] =
        sp[wnc * 112 + cc] + sp[(wnc + 4) * 112 + cc];
  }
}

// ---- k4a0: reduce per-block sums -> sumU/sumV (no atomics) ----
__global__ void k4a0_redsum(const float* __restrict__ sumP,
                            float* __restrict__ sumU, float* __restrict__ sumV) {
  __shared__ float red[4];
  const int c = blockIdx.x;          // 0..199
  const int tid = threadIdx.x;       // 256
  float s = 0.f;
  for (int b = tid; b < NBLK2; b += 256) s += sumP[(size_t)b * 200 + c];
#pragma unroll
  for (int off = 1; off < 64; off <<= 1) s += __shfl_xor(s, off, 64);
  if ((tid & 63) == 0) red[tid >> 6] = s;
  __syncthreads();
  if (tid == 0) {
    float t = red[0] + red[1] + red[2] + red[3];
    if (c < 100) sumU[c] = t; else sumV[c - 100] = t;
  }
}

// ---- k4a: Dscale ----
__global__ void k4a_norm(const float* __restrict__ sumU, const float* __restrict__ sumV,
                         float* __restrict__ dsc) {
  const int l = threadIdx.x;  // 64
  float v = 0.f;
  if (l < 50) v = sumU[l] * sumV[l] + sumU[l + 50] * sumV[l + 50];
#pragma unroll
  for (int off = 32; off > 0; off >>= 1) v += __shfl_down(v, off, 64);
  if (l == 0) dsc[0] = 1.f / (v * (1.f / (float)NROWS) + 1e-6f);
}

// ---- k4b: reduce 98 f32 partials, scale, store transposed bf16 [j][128] ----
__global__ void k4b_final(const float* __restrict__ part, const float* __restrict__ dsc,
                          bf16* __restrict__ vtzt) {
  const int idx = blockIdx.x * 256 + threadIdx.x;   // 49 blocks
  if (idx < 1792) vtzt[(idx >> 4) * 128 + 112 + (idx & 15)] = (bf16)0.f;
  if (idx >= 12544) return;
  const int i = idx / 112;
  const int j = idx % 112;
  float s = 0.f;
#pragma unroll 7
  for (int bb = 0; bb < 98; ++bb) s += part[(size_t)bb * 12544 + idx];
  vtzt[j * 128 + i] = (bf16)(s * dsc[0]);
}

// ---- k5: res = U @ VtZS -> out[:, 0:100] ----
__global__ __launch_bounds__(256) void k5_res(
    const bf16* __restrict__ U, const bf16* __restrict__ vtzt,
    float* __restrict__ out) {
  const int tid = threadIdx.x;
  const int lane = tid & 63;
  const int wave = tid >> 6;
  const int m = lane & 15, g = lane >> 4;
  const int rb = blockIdx.x * 128 + wave * 32;

  f32x4 acc[2][7];
#pragma unroll
  for (int i = 0; i < 2; ++i)
#pragma unroll
    for (int j = 0; j < 7; ++j) acc[i][j] = (f32x4){0.f, 0.f, 0.f, 0.f};

  int r0 = rb + m;      if (r0 > NROWS - 1) r0 = NROWS - 1;
  int r1 = rb + 16 + m; if (r1 > NROWS - 1) r1 = NROWS - 1;
  const bf16* u0 = U + (size_t)r0 * 128 + 4 * g;
  const bf16* u1 = U + (size_t)r1 * 128 + 4 * g;
  const bf16* vb = vtzt + 4 * g;

#pragma unroll
  for (int ks = 0; ks < 4; ++ks) {
    bf16x4 A00 = *(const bf16x4*)(u0 + ks * 32);
    bf16x4 A01 = *(const bf16x4*)(u0 + ks * 32 + 16);
    bf16x4 A10 = *(const bf16x4*)(u1 + ks * 32);
    bf16x4 A11 = *(const bf16x4*)(u1 + ks * 32 + 16);
    bf16x8 af0 = {A00[0], A00[1], A00[2], A00[3], A01[0], A01[1], A01[2], A01[3]};
    bf16x8 af1 = {A10[0], A10[1], A10[2], A10[3], A11[0], A11[1], A11[2], A11[3]};
#pragma unroll
    for (int nf = 0; nf < 7; ++nf) {
      const int n = nf * 16 + m;
      bf16x4 B0 = *(const bf16x4*)(vb + n * 128 + ks * 32);
      bf16x4 B1 = *(const bf16x4*)(vb + n * 128 + ks * 32 + 16);
      bf16x8 bfr = {B0[0], B0[1], B0[2], B0[3], B1[0], B1[1], B1[2], B1[3]};
      acc[0][nf] = __builtin_amdgcn_mfma_f32_16x16x32_bf16(af0, bfr, acc[0][nf], 0, 0, 0);
      acc[1][nf] = __builtin_amdgcn_mfma_f32_16x16x32_bf16(af1, bfr, acc[1][nf], 0, 0, 0);
    }
  }
#pragma unroll
  for (int mf = 0; mf < 2; ++mf)
#pragma unroll
    for (int nf = 0; nf < 7; ++nf)
#pragma unroll
      for (int r = 0; r < 4; ++r) {
        const int row = rb + mf * 16 + 4 * g + r;
        const int c = nf * 16 + m;
        if (row < NROWS && c < 100)
          out[(size_t)row * 200 + c] = acc[mf][nf][r];
      }
}

extern "C" void kernel_launch(void* const* d_in, const int* in_sizes, int n_in,
                              void* d_out, int out_size, void* d_ws, size_t ws_size,
                              hipStream_t stream) {
  const float* X = (const float*)d_in[0];
  const float* W = (const float*)d_in[1];
  const float* b = (const float*)d_in[2];
  float* out = (float*)d_out;
  char* ws = (char*)d_ws;
  if (ws_size < WS_NEED) return;

  bf16* wp     = (bf16*)(ws + WS_WP);
  float* sumU  = (float*)(ws + WS_SUMU);
  float* sumV  = (float*)(ws + WS_SUMV);
  float* dsc   = (float*)(ws + WS_DSC);
  bf16* vtzt   = (bf16*)(ws + WS_VTZT);
  bf16* U      = (bf16*)(ws + WS_U);
  float* part  = (float*)(ws + WS_PART);
  float* sumP  = (float*)(ws + WS_SUMP);

  k1_prep<<<896, 256, 0, stream>>>(W, wp, sumU);
  hipMemsetAsync(part, 0, 98u * 12544u * 4u, stream);
  k2_main<<<NBLK2, 512, 0, stream>>>(X, wp, b, out, U, part, sumP);
  k4a0_redsum<<<200, 256, 0, stream>>>(sumP, sumU, sumV);
  k4a_norm<<<1, 64, 0, stream>>>(sumU, sumV, dsc);
  k4b_final<<<49, 256, 0, stream>>>(part, dsc, vtzt);
  k5_res<<<782, 256, 0, stream>>>(U, vtzt, out);
}